// Round 3
// baseline (361.018 us; speedup 1.0000x reference)
//
#include <hip/hip_runtime.h>

typedef _Float16 f16x8 __attribute__((ext_vector_type(8)));
typedef _Float16 f16x4 __attribute__((ext_vector_type(4)));
typedef _Float16 f16x2 __attribute__((ext_vector_type(2)));
typedef float    f32x4 __attribute__((ext_vector_type(4)));

#define MFMA16(a, b, c) __builtin_amdgcn_mfma_f32_16x16x32_f16((a), (b), (c), 0, 0, 0)

static constexpr int SEQ   = 2048;
static constexpr int DIM   = 128;
static constexpr int QBLK  = 64;           // q rows per block (16 per wave)
static constexpr int KVBLK = 32;           // kv rows per tile
static constexpr int NKT   = SEQ / KVBLK;  // 64
static constexpr int BH    = 2 * 16;
static constexpr int KSTR  = 136;          // K LDS row stride (f16): 272B -> conflict-free padded
static constexpr int VSTR  = 40;           // Vt LDS row stride (f16): 80B  -> slot = 5d+lg, 5 coprime 8

// o = exp(QK^T - rowmax) @ V  (unnormalized, fp32 in/out)
// Swapped-operand: S^T = mfma(K,Q); in-register online softmax (q = lr per lane);
// P redistributed via shfl; O^T = mfma(V^T, P^T). f16x3 QK^T for fp32-grade scores.
__global__ __launch_bounds__(256, 4)
void fa_fwd_kernel(const float* __restrict__ Qg, const float* __restrict__ Kg,
                   const float* __restrict__ Vg, float* __restrict__ Og)
{
    __shared__ __align__(16) _Float16 Ksh[KVBLK * KSTR];
    __shared__ __align__(16) _Float16 Ksl[KVBLK * KSTR];
    __shared__ __align__(16) _Float16 Vt[DIM * VSTR];

    const int tid  = threadIdx.x;
    const int wv   = tid >> 6;
    const int lane = tid & 63;
    const int lr   = lane & 15;   // q column owned by this lane
    const int lg   = lane >> 4;   // 0..3

    // XCD-aware swizzle: all 32 q-tiles of one bh on one XCD -> K/V L2-resident.
    const int bi = blockIdx.x;
    const int bh = (bi & 7) + 8 * ((bi >> 3) >> 5);
    const int qt = (bi >> 3) & 31;

    const size_t base = (size_t)bh * SEQ * DIM;
    const float* Qp = Qg + base;
    const float* Kp = Kg + base;
    const float* Vp = Vg + base;
    float*       Op = Og + base;

    const int q0 = qt * QBLK + wv * 16;

    // ---- Q fragments (B-operand: col q = lr, elems d = dc*32 + lg*8 + e), f16 hi/lo
    f16x8 qh[4], ql[4];
    {
        const float* qs = Qp + (size_t)(q0 + lr) * DIM + lg * 8;
#pragma unroll
        for (int dc = 0; dc < 4; ++dc) {
            const float4 a = *(const float4*)(qs + dc * 32);
            const float4 b = *(const float4*)(qs + dc * 32 + 4);
            float xs[8] = {a.x, a.y, a.z, a.w, b.x, b.y, b.z, b.w};
            f16x8 h, l;
#pragma unroll
            for (int e = 0; e < 8; ++e) {
                _Float16 hh = (_Float16)xs[e];
                h[e] = hh;
                l[e] = (_Float16)(xs[e] - (float)hh);
            }
            qh[dc] = h; ql[dc] = l;
        }
    }

    // O^T accumulators: acc[dm] rows d = dm*16 + lg*4 + r, col q = lr
    f32x4 acc[8];
#pragma unroll
    for (int d = 0; d < 8; ++d)
#pragma unroll
        for (int r = 0; r < 4; ++r) acc[d][r] = 0.0f;

    float mrow  = -3.0e38f;   // running (possibly deferred) max for q = lr
    float mtrue = -3.0e38f;   // true running max (for final correction)

    // staging maps
    const int ksr = tid >> 3, kc0 = (tid & 7) * 16;   // K: 8 threads/row, 16 floats each
    const int vk  = (tid >> 5) * 4;                   // V: 4 k-rows
    const int vd0 = (tid & 31) * 4;                   //    x 4 d-cols per thread
    const float* kb = Kp + (size_t)ksr * DIM + kc0;
    const float* vb = Vp + (size_t)vk * DIM + vd0;

    float4 kreg[4], vreg[4];
    // prologue: prefetch tile 0
#pragma unroll
    for (int t = 0; t < 4; ++t) kreg[t] = *(const float4*)(kb + t * 4);
#pragma unroll
    for (int t = 0; t < 4; ++t) vreg[t] = *(const float4*)(vb + (size_t)t * DIM);

    for (int kt = 0; kt < NKT; ++kt) {
        __syncthreads();   // previous tile's LDS reads complete

        // ---- stage K hi/lo (b128 writes, padded stride: conflict-free)
#pragma unroll
        for (int g = 0; g < 2; ++g) {
            float xs[8] = {kreg[2*g].x, kreg[2*g].y, kreg[2*g].z, kreg[2*g].w,
                           kreg[2*g+1].x, kreg[2*g+1].y, kreg[2*g+1].z, kreg[2*g+1].w};
            f16x8 h, l;
#pragma unroll
            for (int e = 0; e < 8; ++e) {
                _Float16 hh = (_Float16)xs[e];
                h[e] = hh;
                l[e] = (_Float16)(xs[e] - (float)hh);
            }
            const int off = (ksr * KSTR + kc0 + 8 * g) * 2;
            *(f16x8*)((char*)Ksh + off) = h;
            *(f16x8*)((char*)Ksl + off) = l;
        }
        // ---- stage V transposed (register transpose, b64 writes, lane-staggered dj)
#pragma unroll
        for (int dj0 = 0; dj0 < 4; ++dj0) {
            const int dj = (dj0 + tid) & 3;
            f16x4 tv = {(_Float16)(((const float*)&vreg[0])[dj]),
                        (_Float16)(((const float*)&vreg[1])[dj]),
                        (_Float16)(((const float*)&vreg[2])[dj]),
                        (_Float16)(((const float*)&vreg[3])[dj])};
            const int d = vd0 + dj;
            *(f16x4*)((char*)Vt + (d * VSTR + vk) * 2) = tv;
        }
        __syncthreads();

        // ---- prefetch tile kt+1 into regs (latency hides under this tile's compute)
        if (kt + 1 < NKT) {
            const float* ks_ = kb + (size_t)(kt + 1) * KVBLK * DIM;
            const float* vs_ = vb + (size_t)(kt + 1) * KVBLK * DIM;
#pragma unroll
            for (int t = 0; t < 4; ++t) kreg[t] = *(const float4*)(ks_ + t * 4);
#pragma unroll
            for (int t = 0; t < 4; ++t) vreg[t] = *(const float4*)(vs_ + (size_t)t * DIM);
        }

        // ---- S^T = K Q^T (f16x3): st[kf] rows k = kf*16 + lg*4 + r, col q = lr
        f32x4 st[2];
#pragma unroll
        for (int kf = 0; kf < 2; ++kf)
#pragma unroll
            for (int r = 0; r < 4; ++r) st[kf][r] = 0.0f;

        __builtin_amdgcn_s_setprio(1);
#pragma unroll
        for (int kf = 0; kf < 2; ++kf) {
            const int rb = (kf * 16 + lr) * (KSTR * 2) + lg * 16;
#pragma unroll
            for (int dc = 0; dc < 4; ++dc) {
                const int off = rb + dc * 64;
                f16x8 kh = *(const f16x8*)((const char*)Ksh + off);
                f16x8 kl = *(const f16x8*)((const char*)Ksl + off);
                st[kf] = MFMA16(kh, qh[dc], st[kf]);
                st[kf] = MFMA16(kl, qh[dc], st[kf]);
                st[kf] = MFMA16(kh, ql[dc], st[kf]);
            }
        }
        __builtin_amdgcn_s_setprio(0);

        // ---- online softmax in-register (q = lr; 4 lg-lanes share a row)
        float tmax = st[0][0];
#pragma unroll
        for (int kf = 0; kf < 2; ++kf)
#pragma unroll
            for (int r = 0; r < 4; ++r) tmax = fmaxf(tmax, st[kf][r]);
        tmax = fmaxf(tmax, __shfl_xor(tmax, 16));
        tmax = fmaxf(tmax, __shfl_xor(tmax, 32));
        mtrue = fmaxf(mtrue, tmax);

        // defer-max (T13): only rescale when some row grew by > THR
        if (!__all(tmax - mrow <= 4.0f)) {
            const float mn  = fmaxf(mrow, tmax);
            const float scl = __expf(mrow - mn);
            mrow = mn;
#pragma unroll
            for (int d = 0; d < 8; ++d)
#pragma unroll
                for (int r = 0; r < 4; ++r) acc[d][r] *= scl;
        }

        // P^T packed f16 (bounded by e^4)
        int p00, p01, p10, p11;
        {
            f16x2 e0 = {(_Float16)__expf(st[0][0] - mrow), (_Float16)__expf(st[0][1] - mrow)};
            f16x2 e1 = {(_Float16)__expf(st[0][2] - mrow), (_Float16)__expf(st[0][3] - mrow)};
            f16x2 e2 = {(_Float16)__expf(st[1][0] - mrow), (_Float16)__expf(st[1][1] - mrow)};
            f16x2 e3 = {(_Float16)__expf(st[1][2] - mrow), (_Float16)__expf(st[1][3] - mrow)};
            p00 = __builtin_bit_cast(int, e0);
            p01 = __builtin_bit_cast(int, e1);
            p10 = __builtin_bit_cast(int, e2);
            p11 = __builtin_bit_cast(int, e3);
        }

        // ---- redistribute P^T to B-frag: col lr needs k = lg*8 + j
        const int srcA = lr + 16 * ((2 * lg) & 3);
        const int srcB = lr + 16 * ((2 * lg + 1) & 3);
        int a0 = __shfl(p00, srcA), a1 = __shfl(p01, srcA);
        int b0 = __shfl(p00, srcB), b1 = __shfl(p01, srcB);
        int c0 = __shfl(p10, srcA), c1 = __shfl(p11, srcA);
        int d0 = __shfl(p10, srcB), d1 = __shfl(p11, srcB);
        const bool hiF = (lg >> 1) != 0;   // kf = lg>>1
        union { int i[4]; f16x8 v; } u;
        u.i[0] = hiF ? c0 : a0;
        u.i[1] = hiF ? c1 : a1;
        u.i[2] = hiF ? d0 : b0;
        u.i[3] = hiF ? d1 : b1;
        const f16x8 pb = u.v;

        // ---- PV: O^T += V^T P^T  (8 independent MFMAs)
        __builtin_amdgcn_s_setprio(1);
#pragma unroll
        for (int dm = 0; dm < 8; ++dm) {
            const int d = dm * 16 + lr;
            f16x8 va = *(const f16x8*)((const char*)Vt + d * (VSTR * 2) + lg * 16);
            acc[dm] = MFMA16(va, pb, acc[dm]);
        }
        __builtin_amdgcn_s_setprio(0);
    }

    // ---- final correction to the true global row max (reference is unnormalized)
    const float fin = __expf(mrow - mtrue);
#pragma unroll
    for (int dm = 0; dm < 8; ++dm)
#pragma unroll
        for (int r = 0; r < 4; ++r) acc[dm][r] *= fin;

    // ---- store O (rows contiguous in d -> coalesced f32x4)
    float* ob = Op + (size_t)(q0 + lr) * DIM + lg * 4;
#pragma unroll
    for (int dm = 0; dm < 8; ++dm) *(f32x4*)(ob + dm * 16) = acc[dm];
}

extern "C" void kernel_launch(void* const* d_in, const int* in_sizes, int n_in,
                              void* d_out, int out_size, void* d_ws, size_t ws_size,
                              hipStream_t stream) {
    const float* q = (const float*)d_in[0];
    const float* k = (const float*)d_in[1];
    const float* v = (const float*)d_in[2];
    float* o = (float*)d_out;
    dim3 grid((SEQ / QBLK) * BH);   // 1024 blocks, XCD-swizzled in-kernel
    fa_fwd_kernel<<<grid, dim3(256), 0, stream>>>(q, k, v, o);
}

// Round 4
// 192.922 us; speedup vs baseline: 1.8713x; 1.8713x over previous
//
#include <hip/hip_runtime.h>

typedef _Float16 f16x8 __attribute__((ext_vector_type(8)));
typedef _Float16 f16x4 __attribute__((ext_vector_type(4)));
typedef _Float16 f16x2 __attribute__((ext_vector_type(2)));
typedef float    f32x4 __attribute__((ext_vector_type(4)));

#define MFMA16(a, b, c) __builtin_amdgcn_mfma_f32_16x16x32_f16((a), (b), (c), 0, 0, 0)

static constexpr int SEQ   = 2048;
static constexpr int DIM   = 128;
static constexpr int QBLK  = 64;           // q rows per block (16 per wave)
static constexpr int KVBLK = 32;           // kv rows per tile
static constexpr int NKT   = SEQ / KVBLK;  // 64
static constexpr int BH    = 2 * 16;
static constexpr int KSTR  = 136;          // K LDS row stride (f16): 272B padded, conflict-free
static constexpr int VSTR  = 40;           // Vt LDS row stride (f16): 80B, conflict-free both sides

// o = exp(QK^T - rowmax) @ V  (unnormalized, fp32 in/out)
// S^T = mfma(K,Q); in-register online softmax (q = lr per lane); P via shfl;
// O^T = mfma(V^T, P^T). f16x3 QK^T for fp32-grade scores.
__global__ __launch_bounds__(256, 4)
void fa_fwd_kernel(const float* __restrict__ Qg, const float* __restrict__ Kg,
                   const float* __restrict__ Vg, float* __restrict__ Og)
{
    __shared__ __align__(16) _Float16 Ksh[KVBLK * KSTR];
    __shared__ __align__(16) _Float16 Ksl[KVBLK * KSTR];
    __shared__ __align__(16) _Float16 Vt[DIM * VSTR];

    const int tid  = threadIdx.x;
    const int wv   = tid >> 6;
    const int lane = tid & 63;
    const int lr   = lane & 15;   // q column owned by this lane
    const int lg   = lane >> 4;   // 0..3

    // XCD-aware swizzle: all 32 q-tiles of one bh on one XCD -> K/V L2-resident.
    const int bi = blockIdx.x;
    const int bh = (bi & 7) + 8 * ((bi >> 3) >> 5);
    const int qt = (bi >> 3) & 31;

    const size_t base = (size_t)bh * SEQ * DIM;
    const float* Qp = Qg + base;
    const float* Kp = Kg + base;
    const float* Vp = Vg + base;
    float*       Op = Og + base;

    const int q0 = qt * QBLK + wv * 16;

    // ---- Q fragments (B-operand: col q = lr, elems d = dc*32 + lg*8 + e), f16 hi/lo
    f16x8 qh[4], ql[4];
    {
        const float* qs = Qp + (size_t)(q0 + lr) * DIM + lg * 8;
#pragma unroll
        for (int dc = 0; dc < 4; ++dc) {
            const float4 a = *(const float4*)(qs + dc * 32);
            const float4 b = *(const float4*)(qs + dc * 32 + 4);
            float xs[8] = {a.x, a.y, a.z, a.w, b.x, b.y, b.z, b.w};
            f16x8 h, l;
#pragma unroll
            for (int e = 0; e < 8; ++e) {
                _Float16 hh = (_Float16)xs[e];
                h[e] = hh;
                l[e] = (_Float16)(xs[e] - (float)hh);
            }
            qh[dc] = h; ql[dc] = l;
        }
    }

    // O^T accumulators: acc[dm] rows d = dm*16 + lg*4 + r, col q = lr
    f32x4 acc[8];
#pragma unroll
    for (int d = 0; d < 8; ++d)
#pragma unroll
        for (int r = 0; r < 4; ++r) acc[d][r] = 0.0f;

    float mrow  = -3.0e38f;   // running (deferred) max for q = lr
    float mtrue = -3.0e38f;   // true running max (final correction)

    // staging maps (all compile-time register indexing — no scratch)
    const int ksr = tid >> 3, kc0 = (tid & 7) * 16;   // K: 8 threads/row, 16 floats each
    const int vc  = tid & 31;                         // V: d columns {vc, vc+32, vc+64, vc+96}
    const int vk  = (tid >> 5) * 4;                   //    x 4 consecutive k rows
    const float* kb = Kp + (size_t)ksr * DIM + kc0;
    const float* vb = Vp + (size_t)vk * DIM + vc;

    float4 kreg[4];
    float  vreg[4][4];   // [d-col j][k-row r]
    // prologue: prefetch tile 0
#pragma unroll
    for (int t = 0; t < 4; ++t) kreg[t] = *(const float4*)(kb + t * 4);
#pragma unroll
    for (int j = 0; j < 4; ++j)
#pragma unroll
        for (int r = 0; r < 4; ++r) vreg[j][r] = vb[(size_t)r * DIM + 32 * j];

    for (int kt = 0; kt < NKT; ++kt) {
        __syncthreads();   // previous tile's LDS reads complete

        // ---- stage K hi/lo (b128 writes, padded stride: uniform 8 lanes/quartet)
#pragma unroll
        for (int g = 0; g < 2; ++g) {
            float xs[8] = {kreg[2*g].x, kreg[2*g].y, kreg[2*g].z, kreg[2*g].w,
                           kreg[2*g+1].x, kreg[2*g+1].y, kreg[2*g+1].z, kreg[2*g+1].w};
            f16x8 h, l;
#pragma unroll
            for (int e = 0; e < 8; ++e) {
                _Float16 hh = (_Float16)xs[e];
                h[e] = hh;
                l[e] = (_Float16)(xs[e] - (float)hh);
            }
            const int off = (ksr * KSTR + kc0 + 8 * g) * 2;
            *(f16x8*)((char*)Ksh + off) = h;
            *(f16x8*)((char*)Ksl + off) = l;
        }
        // ---- stage V transposed (b64 writes, granule = 10*vc + lane>>5: conflict-free)
#pragma unroll
        for (int j = 0; j < 4; ++j) {
            const int d = vc + 32 * j;
            f16x4 tv = {(_Float16)vreg[j][0], (_Float16)vreg[j][1],
                        (_Float16)vreg[j][2], (_Float16)vreg[j][3]};
            *(f16x4*)((char*)Vt + (d * VSTR + vk) * 2) = tv;
        }
        __syncthreads();

        // ---- prefetch tile kt+1 (latency hides under this tile's compute)
        if (kt + 1 < NKT) {
            const float* ks_ = kb + (size_t)(kt + 1) * KVBLK * DIM;
            const float* vs_ = vb + (size_t)(kt + 1) * KVBLK * DIM;
#pragma unroll
            for (int t = 0; t < 4; ++t) kreg[t] = *(const float4*)(ks_ + t * 4);
#pragma unroll
            for (int j = 0; j < 4; ++j)
#pragma unroll
                for (int r = 0; r < 4; ++r) vreg[j][r] = vs_[(size_t)r * DIM + 32 * j];
        }

        // ---- S^T = K Q^T (f16x3): st[kf] rows k = kf*16 + lg*4 + r, col q = lr
        f32x4 st[2];
#pragma unroll
        for (int kf = 0; kf < 2; ++kf)
#pragma unroll
            for (int r = 0; r < 4; ++r) st[kf][r] = 0.0f;

        __builtin_amdgcn_s_setprio(1);
#pragma unroll
        for (int kf = 0; kf < 2; ++kf) {
            const int rb = (kf * 16 + lr) * (KSTR * 2) + lg * 16;
#pragma unroll
            for (int dc = 0; dc < 4; ++dc) {
                const int off = rb + dc * 64;
                f16x8 kh = *(const f16x8*)((const char*)Ksh + off);
                f16x8 kl = *(const f16x8*)((const char*)Ksl + off);
                st[kf] = MFMA16(kh, qh[dc], st[kf]);
                st[kf] = MFMA16(kl, qh[dc], st[kf]);
                st[kf] = MFMA16(kh, ql[dc], st[kf]);
            }
        }
        __builtin_amdgcn_s_setprio(0);

        // ---- online softmax in-register (q = lr; 4 lg-lanes share a row)
        float tmax = st[0][0];
#pragma unroll
        for (int kf = 0; kf < 2; ++kf)
#pragma unroll
            for (int r = 0; r < 4; ++r) tmax = fmaxf(tmax, st[kf][r]);
        tmax = fmaxf(tmax, __shfl_xor(tmax, 16));
        tmax = fmaxf(tmax, __shfl_xor(tmax, 32));
        mtrue = fmaxf(mtrue, tmax);

        // defer-max (T13): only rescale when some row grew by > THR
        if (!__all(tmax - mrow <= 4.0f)) {
            const float mn  = fmaxf(mrow, tmax);
            const float scl = __expf(mrow - mn);
            mrow = mn;
#pragma unroll
            for (int d = 0; d < 8; ++d)
#pragma unroll
                for (int r = 0; r < 4; ++r) acc[d][r] *= scl;
        }

        // P^T packed f16 (bounded by e^4)
        int p00, p01, p10, p11;
        {
            f16x2 e0 = {(_Float16)__expf(st[0][0] - mrow), (_Float16)__expf(st[0][1] - mrow)};
            f16x2 e1 = {(_Float16)__expf(st[0][2] - mrow), (_Float16)__expf(st[0][3] - mrow)};
            f16x2 e2 = {(_Float16)__expf(st[1][0] - mrow), (_Float16)__expf(st[1][1] - mrow)};
            f16x2 e3 = {(_Float16)__expf(st[1][2] - mrow), (_Float16)__expf(st[1][3] - mrow)};
            p00 = __builtin_bit_cast(int, e0);
            p01 = __builtin_bit_cast(int, e1);
            p10 = __builtin_bit_cast(int, e2);
            p11 = __builtin_bit_cast(int, e3);
        }

        // ---- redistribute P^T to B-frag: col lr needs k = lg*8 + j
        const int srcA = lr + 16 * ((2 * lg) & 3);
        const int srcB = lr + 16 * ((2 * lg + 1) & 3);
        int a0 = __shfl(p00, srcA), a1 = __shfl(p01, srcA);
        int b0 = __shfl(p00, srcB), b1 = __shfl(p01, srcB);
        int c0 = __shfl(p10, srcA), c1 = __shfl(p11, srcA);
        int d0 = __shfl(p10, srcB), d1 = __shfl(p11, srcB);
        const bool hiF = (lg >> 1) != 0;   // kf = lg>>1
        union { int i[4]; f16x8 v; } u;
        u.i[0] = hiF ? c0 : a0;
        u.i[1] = hiF ? c1 : a1;
        u.i[2] = hiF ? d0 : b0;
        u.i[3] = hiF ? d1 : b1;
        const f16x8 pb = u.v;

        // ---- PV: O^T += V^T P^T  (8 independent MFMAs)
        __builtin_amdgcn_s_setprio(1);
#pragma unroll
        for (int dm = 0; dm < 8; ++dm) {
            const int d = dm * 16 + lr;
            f16x8 va = *(const f16x8*)((const char*)Vt + d * (VSTR * 2) + lg * 16);
            acc[dm] = MFMA16(va, pb, acc[dm]);
        }
        __builtin_amdgcn_s_setprio(0);
    }

    // ---- final correction to the true global row max (reference is unnormalized)
    const float fin = __expf(mrow - mtrue);
#pragma unroll
    for (int dm = 0; dm < 8; ++dm)
#pragma unroll
        for (int r = 0; r < 4; ++r) acc[dm][r] *= fin;

    // ---- store O (rows contiguous in d -> coalesced f32x4)
    float* ob = Op + (size_t)(q0 + lr) * DIM + lg * 4;
#pragma unroll
    for (int dm = 0; dm < 8; ++dm) *(f32x4*)(ob + dm * 16) = acc[dm];
}

extern "C" void kernel_launch(void* const* d_in, const int* in_sizes, int n_in,
                              void* d_out, int out_size, void* d_ws, size_t ws_size,
                              hipStream_t stream) {
    const float* q = (const float*)d_in[0];
    const float* k = (const float*)d_in[1];
    const float* v = (const float*)d_in[2];
    float* o = (float*)d_out;
    dim3 grid((SEQ / QBLK) * BH);   // 1024 blocks, XCD-swizzled in-kernel
    fa_fwd_kernel<<<grid, dim3(256), 0, stream>>>(q, k, v, o);
}

// Round 6
// 130.178 us; speedup vs baseline: 2.7733x; 1.4820x over previous
//
#include <hip/hip_runtime.h>

typedef _Float16 f16x8  __attribute__((ext_vector_type(8)));
typedef _Float16 f16x4  __attribute__((ext_vector_type(4)));
typedef _Float16 f16x2  __attribute__((ext_vector_type(2)));
typedef float    f32x4  __attribute__((ext_vector_type(4)));
typedef float    f32x16 __attribute__((ext_vector_type(16)));

#define MFMA32(a, b, c) __builtin_amdgcn_mfma_f32_32x32x16_f16((a), (b), (c), 0, 0, 0)

static constexpr int SEQ   = 2048;
static constexpr int DIM   = 128;
static constexpr int QBLK  = 128;          // 4 waves x 32 q-rows
static constexpr int KVBLK = 32;           // kv rows per tile
static constexpr int NKT   = SEQ / KVBLK;  // 64
static constexpr int BH    = 2 * 16;
static constexpr int KSTR  = 136;          // K LDS row stride (f16), 272B: conflict-free
static constexpr int VSTR  = 40;           // Vt LDS row stride (f16), 80B: conflict-free

// o = exp(QK^T - rowmax) @ V  (unnormalized, fp32 in/out)
// 32x32x16 MFMA; S^T = mfma(Khi,Qhi)+mfma(Khi,Qlo); in-register softmax
// (q-col = lane&31, halves combined via shfl_xor 32); P exchanged across
// halves with 2 shfl_xor per k-step; O^T = mfma(V^T, P^T).
__global__ __launch_bounds__(256, 2)
void fa_fwd_kernel(const float* __restrict__ Qg, const float* __restrict__ Kg,
                   const float* __restrict__ Vg, float* __restrict__ Og)
{
    __shared__ __align__(16) _Float16 Ksh[KVBLK * KSTR];
    __shared__ __align__(16) _Float16 Vt[DIM * VSTR];

    const int tid  = threadIdx.x;
    const int wv   = tid >> 6;
    const int lane = tid & 63;
    const int lq   = lane & 31;   // q column (and K/V A-row) owned by this lane
    const int lh   = lane >> 5;   // half: 0/1

    // XCD swizzle: 512 blocks; all 16 q-tiles of one bh -> one XCD (K/V L2-resident)
    const int bi = blockIdx.x;
    const int bh = (bi & 7) + 8 * (bi >> 7);
    const int qt = (bi >> 3) & 15;

    const size_t base = (size_t)bh * SEQ * DIM;
    const float* Qp = Qg + base;
    const float* Kp = Kg + base;
    const float* Vp = Vg + base;
    float*       Op = Og + base;

    const int q0 = qt * QBLK + wv * 32;

    // ---- Q fragments (B-operand: col q = lq, elems d = 16t + 8*lh + j), f16 hi/lo
    f16x8 qh[8], ql[8];
    {
        const float* qs = Qp + (size_t)(q0 + lq) * DIM + 8 * lh;
#pragma unroll
        for (int t = 0; t < 8; ++t) {
            const float4 a = *(const float4*)(qs + 16 * t);
            const float4 b = *(const float4*)(qs + 16 * t + 4);
            float xs[8] = {a.x, a.y, a.z, a.w, b.x, b.y, b.z, b.w};
            f16x8 h, l;
#pragma unroll
            for (int e = 0; e < 8; ++e) {
                _Float16 hh = (_Float16)xs[e];
                h[e] = hh;
                l[e] = (_Float16)(xs[e] - (float)hh);
            }
            qh[t] = h; ql[t] = l;
        }
    }

    // O^T accumulators: acc[dm][r] = O^T[d = 32*dm + (r&3)+8*(r>>2)+4*lh][q = lq]
    f32x16 acc[4];
#pragma unroll
    for (int a = 0; a < 4; ++a)
#pragma unroll
        for (int r = 0; r < 16; ++r) acc[a][r] = 0.0f;

    float mrow  = -3.0e38f;   // running (deferred) max for q = lq
    float mtrue = -3.0e38f;   // true running max

    // staging maps (all static register indexing)
    const int ksr = tid >> 3, kc0 = (tid & 7) * 16;   // K: 8 threads/row, 16 floats
    const int vc  = tid & 31;                         // V: d cols {vc,vc+32,vc+64,vc+96}
    const int vk  = (tid >> 5) * 4;                   //    x 4 consecutive k rows
    const float* kb = Kp + (size_t)ksr * DIM + kc0;
    const float* vb = Vp + (size_t)vk * DIM + vc;

    float4 kreg[4];
    float  vreg[4][4];   // [d-col j][k-row r]
#pragma unroll
    for (int t = 0; t < 4; ++t) kreg[t] = *(const float4*)(kb + t * 4);
#pragma unroll
    for (int j = 0; j < 4; ++j)
#pragma unroll
        for (int r = 0; r < 4; ++r) vreg[j][r] = vb[(size_t)r * DIM + 32 * j];

    for (int kt = 0; kt < NKT; ++kt) {
        __syncthreads();   // previous tile's LDS reads complete

        // ---- stage K hi (b128 writes, padded stride: conflict-free)
#pragma unroll
        for (int g = 0; g < 2; ++g) {
            float xs[8] = {kreg[2*g].x, kreg[2*g].y, kreg[2*g].z, kreg[2*g].w,
                           kreg[2*g+1].x, kreg[2*g+1].y, kreg[2*g+1].z, kreg[2*g+1].w};
            f16x8 h;
#pragma unroll
            for (int e = 0; e < 8; ++e) h[e] = (_Float16)xs[e];
            *(f16x8*)((char*)Ksh + (ksr * KSTR + kc0 + 8 * g) * 2) = h;
        }
        // ---- stage V transposed (b64 writes, conflict-free)
#pragma unroll
        for (int j = 0; j < 4; ++j) {
            const int d = vc + 32 * j;
            f16x4 tv = {(_Float16)vreg[j][0], (_Float16)vreg[j][1],
                        (_Float16)vreg[j][2], (_Float16)vreg[j][3]};
            *(f16x4*)((char*)Vt + (d * VSTR + vk) * 2) = tv;
        }
        __syncthreads();

        // ---- prefetch tile kt+1 (hides under this tile's compute)
        if (kt + 1 < NKT) {
            const float* ks_ = kb + (size_t)(kt + 1) * KVBLK * DIM;
            const float* vs_ = vb + (size_t)(kt + 1) * KVBLK * DIM;
#pragma unroll
            for (int t = 0; t < 4; ++t) kreg[t] = *(const float4*)(ks_ + t * 4);
#pragma unroll
            for (int j = 0; j < 4; ++j)
#pragma unroll
                for (int r = 0; r < 4; ++r) vreg[j][r] = vs_[(size_t)r * DIM + 32 * j];
        }

        // ---- S^T = Khi Q^T (qh + ql passes, split accumulator chains)
        f32x16 s0, s1;
#pragma unroll
        for (int r = 0; r < 16; ++r) { s0[r] = 0.0f; s1[r] = 0.0f; }
        __builtin_amdgcn_s_setprio(1);
#pragma unroll
        for (int t = 0; t < 8; ++t) {
            f16x8 kh = *(const f16x8*)((const char*)Ksh + (lq * KSTR + 16 * t + 8 * lh) * 2);
            s0 = MFMA32(kh, qh[t], s0);
            s1 = MFMA32(kh, ql[t], s1);
        }
        __builtin_amdgcn_s_setprio(0);
        f32x16 st = s0 + s1;   // st[r] = S^T[k = (r&3)+8*(r>>2)+4*lh][q = lq]

        // ---- online softmax (halves l and l^32 share q-col lq)
        float tmax = fmaxf(fmaxf(fmaxf(st[0], st[1]), fmaxf(st[2], st[3])),
                           fmaxf(fmaxf(st[4], st[5]), fmaxf(st[6], st[7])));
        tmax = fmaxf(tmax, fmaxf(fmaxf(fmaxf(st[8], st[9]), fmaxf(st[10], st[11])),
                                 fmaxf(fmaxf(st[12], st[13]), fmaxf(st[14], st[15]))));
        tmax = fmaxf(tmax, __shfl_xor(tmax, 32));
        mtrue = fmaxf(mtrue, tmax);

        // defer-max (T13): rescale only when some row grew by > THR
        if (!__all(tmax - mrow <= 4.0f)) {
            const float mn  = fmaxf(mrow, tmax);
            const float scl = __expf(mrow - mn);
            mrow = mn;
#pragma unroll
            for (int a = 0; a < 4; ++a)
#pragma unroll
                for (int r = 0; r < 16; ++r) acc[a][r] *= scl;
        }

        // ---- P^T packed f16 (bounded by e^4)
        // pk[i] holds {P[k0], P[k0+1]} with k0 = (2i&3)+8*(i>>1)+4*lh (pairs of st)
        int pk[8];
#pragma unroll
        for (int i = 0; i < 8; ++i) {
            f16x2 e = {(_Float16)__expf(st[2 * i] - mrow),
                       (_Float16)__expf(st[2 * i + 1] - mrow)};
            pk[i] = __builtin_bit_cast(int, e);
        }

        // ---- PV: O^T += V^T P^T.  B-frag for k-step s (col lq, k = 16s+8lh+j):
        //   lh=0 needs {pk[4s],pk[4s+1]} (own) + {pk[4s],pk[4s+1]} from partner (lh=1)
        //   lh=1 needs {pk[4s+2],pk[4s+3]} from partner (lh=0) + own {pk[4s+2],pk[4s+3]}
        // One shfl_xor serves both directions by pre-selecting the outgoing word.
#pragma unroll
        for (int s = 0; s < 2; ++s) {
            const int z1 = __shfl_xor(lh ? pk[4*s+0] : pk[4*s+2], 32);
            const int z2 = __shfl_xor(lh ? pk[4*s+1] : pk[4*s+3], 32);
            union { int i[4]; f16x8 v; } u;
            u.i[0] = lh ? z1 : pk[4*s+0];
            u.i[1] = lh ? z2 : pk[4*s+1];
            u.i[2] = lh ? pk[4*s+2] : z1;
            u.i[3] = lh ? pk[4*s+3] : z2;
            const f16x8 pb = u.v;
            __builtin_amdgcn_s_setprio(1);
#pragma unroll
            for (int dm = 0; dm < 4; ++dm) {
                const int d = dm * 32 + lq;
                f16x8 va = *(const f16x8*)((const char*)Vt + (d * VSTR + 16 * s + 8 * lh) * 2);
                acc[dm] = MFMA32(va, pb, acc[dm]);
            }
            __builtin_amdgcn_s_setprio(0);
        }
    }

    // ---- final correction to the true global row max (reference is unnormalized)
    const float fin = __expf(mrow - mtrue);
#pragma unroll
    for (int a = 0; a < 4; ++a)
#pragma unroll
        for (int r = 0; r < 16; ++r) acc[a][r] *= fin;

    // ---- store O: reg r of acc[dm] -> col d = 32*dm + 8*(r>>2) + 4*lh + (r&3)
    float* ob = Op + (size_t)(q0 + lq) * DIM + 4 * lh;
#pragma unroll
    for (int dm = 0; dm < 4; ++dm)
#pragma unroll
        for (int kp = 0; kp < 4; ++kp) {
            f32x4 v4 = {acc[dm][4*kp], acc[dm][4*kp+1], acc[dm][4*kp+2], acc[dm][4*kp+3]};
            *(f32x4*)(ob + dm * 32 + kp * 8) = v4;
        }
}

extern "C" void kernel_launch(void* const* d_in, const int* in_sizes, int n_in,
                              void* d_out, int out_size, void* d_ws, size_t ws_size,
                              hipStream_t stream) {
    const float* q = (const float*)d_in[0];
    const float* k = (const float*)d_in[1];
    const float* v = (const float*)d_in[2];
    float* o = (float*)d_out;
    dim3 grid((SEQ / QBLK) * BH);   // 512 blocks = 2/CU exact, XCD-swizzled in-kernel
    fa_fwd_kernel<<<grid, dim3(256), 0, stream>>>(q, k, v, o);
}

// Round 7
// 121.526 us; speedup vs baseline: 2.9707x; 1.0712x over previous
//
#include <hip/hip_runtime.h>

typedef _Float16 f16x8  __attribute__((ext_vector_type(8)));
typedef _Float16 f16x4  __attribute__((ext_vector_type(4)));
typedef _Float16 f16x2  __attribute__((ext_vector_type(2)));
typedef float    f32x4  __attribute__((ext_vector_type(4)));
typedef float    f32x16 __attribute__((ext_vector_type(16)));

#define MFMA32(a, b, c) __builtin_amdgcn_mfma_f32_32x32x16_f16((a), (b), (c), 0, 0, 0)

static constexpr int SEQ   = 2048;
static constexpr int DIM   = 128;
static constexpr int QBLK  = 128;          // 4 waves x 32 q-rows
static constexpr int KVBLK = 32;           // kv rows per tile
static constexpr int NKT   = SEQ / KVBLK;  // 64
static constexpr int BH    = 2 * 16;
static constexpr int KSTR  = 136;          // K LDS row stride (f16), 272B: conflict-free
static constexpr int VSTR  = 40;           // Vt LDS row stride (f16), 80B: conflict-free

// o = exp(QK^T - rowmax) @ V  (unnormalized, fp32 in/out)
// 32x32x16 MFMA; Q pre-scaled by log2(e) so softmax runs in exp2 domain.
// S^T = mfma(Khi, Qhi) single-pass (2 interleaved acc chains); in-register
// softmax (q-col = lane&31, halves combined via shfl_xor 32); P exchanged
// across halves with 2 shfl_xor per k-step; O^T = mfma(V^T, P^T).
__global__ __launch_bounds__(256, 2)
void fa_fwd_kernel(const float* __restrict__ Qg, const float* __restrict__ Kg,
                   const float* __restrict__ Vg, float* __restrict__ Og)
{
    __shared__ __align__(16) _Float16 Ksh[KVBLK * KSTR];
    __shared__ __align__(16) _Float16 Vt[DIM * VSTR];

    const int tid  = threadIdx.x;
    const int wv   = tid >> 6;
    const int lane = tid & 63;
    const int lq   = lane & 31;   // q column (and K/V A-row) owned by this lane
    const int lh   = lane >> 5;   // half: 0/1

    // XCD swizzle: 512 blocks; all 16 q-tiles of one bh -> one XCD (K/V L2-resident)
    const int bi = blockIdx.x;
    const int bh = (bi & 7) + 8 * (bi >> 7);
    const int qt = (bi >> 3) & 15;

    const size_t base = (size_t)bh * SEQ * DIM;
    const float* Qp = Qg + base;
    const float* Kp = Kg + base;
    const float* Vp = Vg + base;
    float*       Op = Og + base;

    const int q0 = qt * QBLK + wv * 32;

    // ---- Q fragment (B-operand: col q = lq, elems d = 16t + 8*lh + j)
    // scaled by log2(e): softmax then uses exp2 directly.
    constexpr float LOG2E = 1.44269504088896340736f;
    f16x8 qh[8];
    {
        const float* qs = Qp + (size_t)(q0 + lq) * DIM + 8 * lh;
#pragma unroll
        for (int t = 0; t < 8; ++t) {
            const float4 a = *(const float4*)(qs + 16 * t);
            const float4 b = *(const float4*)(qs + 16 * t + 4);
            float xs[8] = {a.x, a.y, a.z, a.w, b.x, b.y, b.z, b.w};
            f16x8 h;
#pragma unroll
            for (int e = 0; e < 8; ++e) h[e] = (_Float16)(xs[e] * LOG2E);
            qh[t] = h;
        }
    }

    // O^T accumulators: acc[dm][r] = O^T[d = 32*dm + (r&3)+8*(r>>2)+4*lh][q = lq]
    f32x16 acc[4];
#pragma unroll
    for (int a = 0; a < 4; ++a)
#pragma unroll
        for (int r = 0; r < 16; ++r) acc[a][r] = 0.0f;

    float mrow  = -3.0e38f;   // running (deferred) max, log2 units
    float mtrue = -3.0e38f;   // true running max, log2 units

    // staging maps (all static register indexing)
    const int ksr = tid >> 3, kc0 = (tid & 7) * 16;   // K: 8 threads/row, 16 floats
    const int vc  = tid & 31;                         // V: d cols {vc,vc+32,vc+64,vc+96}
    const int vk  = (tid >> 5) * 4;                   //    x 4 consecutive k rows
    const float* kb = Kp + (size_t)ksr * DIM + kc0;
    const float* vb = Vp + (size_t)vk * DIM + vc;

    float4 kreg[4];
    float  vreg[4][4];   // [d-col j][k-row r]
#pragma unroll
    for (int t = 0; t < 4; ++t) kreg[t] = *(const float4*)(kb + t * 4);
#pragma unroll
    for (int j = 0; j < 4; ++j)
#pragma unroll
        for (int r = 0; r < 4; ++r) vreg[j][r] = vb[(size_t)r * DIM + 32 * j];

    for (int kt = 0; kt < NKT; ++kt) {
        __syncthreads();   // previous tile's LDS reads complete

        // ---- stage K hi (b128 writes, padded stride: conflict-free)
#pragma unroll
        for (int g = 0; g < 2; ++g) {
            float xs[8] = {kreg[2*g].x, kreg[2*g].y, kreg[2*g].z, kreg[2*g].w,
                           kreg[2*g+1].x, kreg[2*g+1].y, kreg[2*g+1].z, kreg[2*g+1].w};
            f16x8 h;
#pragma unroll
            for (int e = 0; e < 8; ++e) h[e] = (_Float16)xs[e];
            *(f16x8*)((char*)Ksh + (ksr * KSTR + kc0 + 8 * g) * 2) = h;
        }
        // ---- stage V transposed (b64 writes, conflict-free)
#pragma unroll
        for (int j = 0; j < 4; ++j) {
            const int d = vc + 32 * j;
            f16x4 tv = {(_Float16)vreg[j][0], (_Float16)vreg[j][1],
                        (_Float16)vreg[j][2], (_Float16)vreg[j][3]};
            *(f16x4*)((char*)Vt + (d * VSTR + vk) * 2) = tv;
        }
        __syncthreads();

        // ---- prefetch tile kt+1 (hides under this tile's compute)
        if (kt + 1 < NKT) {
            const float* ks_ = kb + (size_t)(kt + 1) * KVBLK * DIM;
            const float* vs_ = vb + (size_t)(kt + 1) * KVBLK * DIM;
#pragma unroll
            for (int t = 0; t < 4; ++t) kreg[t] = *(const float4*)(ks_ + t * 4);
#pragma unroll
            for (int j = 0; j < 4; ++j)
#pragma unroll
                for (int r = 0; r < 4; ++r) vreg[j][r] = vs_[(size_t)r * DIM + 32 * j];
        }

        // ---- S^T = Khi Q^T, single pass, 2 interleaved accumulator chains
        f32x16 s0, s1;
#pragma unroll
        for (int r = 0; r < 16; ++r) { s0[r] = 0.0f; s1[r] = 0.0f; }
        __builtin_amdgcn_s_setprio(1);
#pragma unroll
        for (int t = 0; t < 4; ++t) {
            f16x8 ka = *(const f16x8*)((const char*)Ksh + (lq * KSTR + 32 * t + 8 * lh) * 2);
            f16x8 kc = *(const f16x8*)((const char*)Ksh + (lq * KSTR + 32 * t + 16 + 8 * lh) * 2);
            s0 = MFMA32(ka, qh[2 * t], s0);
            s1 = MFMA32(kc, qh[2 * t + 1], s1);
        }
        __builtin_amdgcn_s_setprio(0);
        f32x16 st = s0 + s1;   // st[r] = S'^T[k = (r&3)+8*(r>>2)+4*lh][q = lq], log2 units

        // ---- online softmax (halves l and l^32 share q-col lq)
        float tmax = fmaxf(fmaxf(fmaxf(st[0], st[1]), fmaxf(st[2], st[3])),
                           fmaxf(fmaxf(st[4], st[5]), fmaxf(st[6], st[7])));
        tmax = fmaxf(tmax, fmaxf(fmaxf(fmaxf(st[8], st[9]), fmaxf(st[10], st[11])),
                                 fmaxf(fmaxf(st[12], st[13]), fmaxf(st[14], st[15]))));
        tmax = fmaxf(tmax, __shfl_xor(tmax, 32));
        mtrue = fmaxf(mtrue, tmax);

        // defer-max (T13): rescale only when some row grew by > THR (log2 units)
        if (!__all(tmax - mrow <= 6.0f)) {
            const float mn  = fmaxf(mrow, tmax);
            const float scl = __builtin_exp2f(mrow - mn);
            mrow = mn;
#pragma unroll
            for (int a = 0; a < 4; ++a)
#pragma unroll
                for (int r = 0; r < 16; ++r) acc[a][r] *= scl;
        }

        // ---- P^T packed f16 (bounded by 2^6 = 64)
        int pk[8];
#pragma unroll
        for (int i = 0; i < 8; ++i) {
            f16x2 e = {(_Float16)__builtin_exp2f(st[2 * i] - mrow),
                       (_Float16)__builtin_exp2f(st[2 * i + 1] - mrow)};
            pk[i] = __builtin_bit_cast(int, e);
        }

        // ---- PV: O^T += V^T P^T.  B-frag for k-step s (col lq, k = 16s+8lh+j):
        // one shfl_xor serves both directions by pre-selecting the outgoing word.
#pragma unroll
        for (int s = 0; s < 2; ++s) {
            const int z1 = __shfl_xor(lh ? pk[4*s+0] : pk[4*s+2], 32);
            const int z2 = __shfl_xor(lh ? pk[4*s+1] : pk[4*s+3], 32);
            union { int i[4]; f16x8 v; } u;
            u.i[0] = lh ? z1 : pk[4*s+0];
            u.i[1] = lh ? z2 : pk[4*s+1];
            u.i[2] = lh ? pk[4*s+2] : z1;
            u.i[3] = lh ? pk[4*s+3] : z2;
            const f16x8 pb = u.v;
            __builtin_amdgcn_s_setprio(1);
#pragma unroll
            for (int dm = 0; dm < 4; ++dm) {
                const int d = dm * 32 + lq;
                f16x8 va = *(const f16x8*)((const char*)Vt + (d * VSTR + 16 * s + 8 * lh) * 2);
                acc[dm] = MFMA32(va, pb, acc[dm]);
            }
            __builtin_amdgcn_s_setprio(0);
        }
    }

    // ---- final correction to the true global row max (reference is unnormalized)
    const float fin = __builtin_exp2f(mrow - mtrue);
#pragma unroll
    for (int a = 0; a < 4; ++a)
#pragma unroll
        for (int r = 0; r < 16; ++r) acc[a][r] *= fin;

    // ---- store O: reg r of acc[dm] -> col d = 32*dm + 8*(r>>2) + 4*lh + (r&3)
    float* ob = Op + (size_t)(q0 + lq) * DIM + 4 * lh;
#pragma unroll
    for (int dm = 0; dm < 4; ++dm)
#pragma unroll
        for (int kp = 0; kp < 4; ++kp) {
            f32x4 v4 = {acc[dm][4*kp], acc[dm][4*kp+1], acc[dm][4*kp+2], acc[dm][4*kp+3]};
            *(f32x4*)(ob + dm * 32 + kp * 8) = v4;
        }
}

extern "C" void kernel_launch(void* const* d_in, const int* in_sizes, int n_in,
                              void* d_out, int out_size, void* d_ws, size_t ws_size,
                              hipStream_t stream) {
    const float* q = (const float*)d_in[0];
    const float* k = (const float*)d_in[1];
    const float* v = (const float*)d_in[2];
    float* o = (float*)d_out;
    dim3 grid((SEQ / QBLK) * BH);   // 512 blocks = 2/CU exact, XCD-swizzled in-kernel
    fa_fwd_kernel<<<grid, dim3(256), 0, stream>>>(q, k, v, o);
}